// Round 6
// baseline (183.441 us; speedup 1.0000x reference)
//
#include <hip/hip_runtime.h>

// B=2, S=32, C=256, L=640, H=5, D=128.  M = B*S*C = 16384, L = 640 = H*D.
//
// ws layout (bytes):
//   XB   @ 0    : x bf16 [16384][640]   -- reused as attn_out (AT) after attn
//   QB   @ SZ   : q bf16 [16384][640] (col = h*128+d)
//   KB   @ 2SZ  : k bf16 [16384][640]
//   VTB  @ 3SZ  : v transposed bf16 [320 bsh][128 d][256 e]
//   WSTK @ 4SZ  : Wq|Wk|Wv stacked bf16 [2048][640] (rows 1920..2047 = 0)
//   WPAD        : Wp bf16 [768][640] (rows 640..767 = 0)
//   BPB         : bp bf16 [640];  FLAG: u32 (1 = inputs fp32)

typedef unsigned short u16;
typedef __bf16 bf16x8 __attribute__((ext_vector_type(8)));
typedef float f32x4 __attribute__((ext_vector_type(4)));

__device__ __forceinline__ u16 f2bf(float f){
  union { float f; unsigned u; } v; v.f = f;
  unsigned r = v.u + 0x7fffu + ((v.u >> 16) & 1u);
  return (u16)(r >> 16);
}
__device__ __forceinline__ float bf2f(u16 u){
  union { unsigned u; float f; } v; v.u = ((unsigned)u) << 16;
  return v.f;
}

__device__ __forceinline__ void gload16(const u16* g, char* l){
  __builtin_amdgcn_global_load_lds((const __attribute__((address_space(1))) void*)g,
                                   (__attribute__((address_space(3))) void*)l, 16, 0, 0);
}

// ---- attention LDS swizzles (unchanged) ----
__device__ __forceinline__ int k_off (int e, int d){ return e*256 + (((d>>3) ^ (e&7)))*16 + (d&7)*2; }
__device__ __forceinline__ int vt_off(int d, int e){ return d*512 + (((e>>3) ^ (d&7)))*16 + (e&7)*2; }
__device__ __forceinline__ int p_off (int c, int el){ return c*256 + (((el>>3) ^ ((c>>2)&3)))*16 + (el&7)*2; }

// ------------------------------------------------------------------
// Fused dtype-detect + convert; also zero-fills the N-pad rows.
__global__ __launch_bounds__(256) void k_convert_all(
    const void* __restrict__ xsrc, const void* __restrict__ s1, const void* __restrict__ s2,
    const void* __restrict__ s3, const void* __restrict__ s4, const void* __restrict__ s5,
    u16* __restrict__ xb, u16* __restrict__ wstk, u16* __restrict__ wpad,
    u16* __restrict__ bpb, unsigned* __restrict__ flagOut){
  __shared__ unsigned sflag;
  const int tid = threadIdx.x;
  const u16* xs = (const u16*)xsrc;
  if (tid < 64){
    int cnt = 0;
    for (int i = tid; i < 1024; i += 64){
      unsigned e = (xs[2*i] >> 7) & 0xffu;
      cnt += (e >= 143u) ? 1 : 0;
    }
    #pragma unroll
    for (int m = 1; m < 64; m <<= 1) cnt += __shfl_xor(cnt, m);
    if (tid == 0) sflag = (cnt > 16) ? 1u : 0u;
  }
  __syncthreads();
  const unsigned flag = sflag;
  if (blockIdx.x == 0 && tid == 0) *flagOut = flag;

  #pragma unroll
  for (int it = 0; it < 4; ++it){
    size_t i = (size_t)blockIdx.x*1024 + it*256 + tid;
    if (i >= 3072160) break;
    const void* src = nullptr; size_t off = 0; u16* dp = nullptr;
    if (i < 2621440){ src = xsrc; off = i; dp = xb + i*4; }
    else {
      size_t j = i - 2621440;
      if (j < 307200){
        int seg = (int)(j / 102400);
        off = j - (size_t)seg*102400;
        src = (seg==0) ? s1 : (seg==1) ? s2 : s3;
        dp = wstk + j*4;
      } else if (j < 327680){
        ushort4 z = {0,0,0,0}; *(ushort4*)(wstk + j*4) = z; continue;
      } else if (j < 430080){
        off = j - 327680; src = s4; dp = wpad + off*4;
      } else if (j < 450560){
        ushort4 z = {0,0,0,0}; *(ushort4*)(wpad + (j-327680)*4) = z; continue;
      } else { off = j - 450560; src = s5; dp = bpb + off*4; }
    }
    if (flag){
      float4 v = ((const float4*)src)[off];
      ushort4 o;
      o.x = f2bf(v.x); o.y = f2bf(v.y); o.z = f2bf(v.z); o.w = f2bf(v.w);
      *(ushort4*)dp = o;
    } else {
      *(ushort4*)dp = ((const ushort4*)src)[off];
    }
  }
}

// ------------------------------------------------------------------
// 256x256-tile, BK=64, 8-wave (2Mx4N), 512-thread, 8-phase/2-K-tile GEMM.
// REGION READ LEDGER (the round-4/5 bug): LDA(0)@ph0 + LDA(1)@ph2 read BOTH
// A0 and A1 (half chosen by the wave's wr, mh is the 64-row sub-block);
// LDB(0)@ph0 + LDB(1)@ph1 read BOTH B0 and B1 (half chosen by wc>>1).
// Hence: B-regions of buf b are free only after ph1's end barrier; A-regions
// only after ph2's end barrier.  Stage schedule (tile t+2 -> buf b):
//   ph2: stB(b,0), stB(b,1)     ph3: stA(b,0), stA(b,1)
// 8 gloads/wave/iter -> boundary wait vmcnt(8) (tile t+1 landed, t+2 in
// flight); vmcnt(0) at t=8.  Barriers are full compiler fences.
template<int MODE>
__global__ __launch_bounds__(512, 2) void gemm8p(
    const u16* __restrict__ Ag, const u16* __restrict__ Bg,
    const u16* __restrict__ bpw, u16* __restrict__ qb, u16* __restrict__ kb,
    u16* __restrict__ vtb, void* __restrict__ outp, const unsigned* __restrict__ flag){
  __shared__ char lds[131072];
  const int tid = threadIdx.x;
  const int lane = tid & 63, wid = tid >> 6;
  const int g = lane >> 4, lo = lane & 15;
  const int wr = wid >> 2, wc = wid & 3;
  const int m0 = blockIdx.x * 256;
  const int n0 = blockIdx.y * 256;
  bool f32out = false;
  if (MODE == 1) f32out = (*flag != 0u);

  // staging: per gload, 64 lanes = 8 rows x 8 chunks; source chunk pre-swizzled
  const int srow = lane >> 3;
  const int scol = ((lane & 7) ^ (((lane >> 5) & 1) << 1)) * 8;
  const u16* Abase = Ag + (size_t)(m0 + wid*16 + srow)*640 + scol;
  const u16* Bbase = Bg + (size_t)(n0 + wid*16 + srow)*640 + scol;

  auto stA = [&](int b, int ah, int kt){
    const u16* s = Abase + (size_t)ah*128*640 + kt*64;
    char* d = lds + b*65536 + ah*16384 + wid*2048;
    gload16(s, d);
    gload16(s + 8*640, d + 1024);
  };
  auto stB = [&](int b, int bh, int kt){
    const u16* s = Bbase + (size_t)bh*128*640 + kt*64;
    char* d = lds + b*65536 + 32768 + bh*16384 + wid*2048;
    gload16(s, d);
    gload16(s + 8*640, d + 1024);
  };

  // read-side swizzled chunk offsets (row bit2 = lo bit2)
  const int cswz = ((lo >> 2) & 1) << 1;
  const int coff0 = ((0*4 + g) ^ cswz) * 16;
  const int coff1 = ((1*4 + g) ^ cswz) * 16;
  const int aBase0 = wr*16384 + lo*128;
  const int bBase0 = 32768 + (wc>>1)*16384 + (wc&1)*8192 + lo*128;

  f32x4 acc[8][4];
  const f32x4 vzero = {0.f, 0.f, 0.f, 0.f};
  #pragma unroll
  for (int i2 = 0; i2 < 8; ++i2)
    #pragma unroll
    for (int j2 = 0; j2 < 4; ++j2) acc[i2][j2] = vzero;
  bf16x8 ar[4][2], br[4][2];

  #define LDA(mh) do { _Pragma("unroll")                                      \
    for (int q = 0; q < 4; ++q){                                              \
      ar[q][0] = *(const bf16x8*)(bufp + aBase0 + (mh)*8192 + q*2048 + coff0);\
      ar[q][1] = *(const bf16x8*)(bufp + aBase0 + (mh)*8192 + q*2048 + coff1);\
    } } while(0)
  #define LDB(nh) do { _Pragma("unroll")                                      \
    for (int q = 0; q < 2; ++q){                                              \
      br[(nh)*2+q][0] = *(const bf16x8*)(bufp + bBase0 + ((nh)*2+q)*2048 + coff0);\
      br[(nh)*2+q][1] = *(const bf16x8*)(bufp + bBase0 + ((nh)*2+q)*2048 + coff1);\
    } } while(0)
  #define MFMAQ(mh, nh) do { _Pragma("unroll")                                \
    for (int q = 0; q < 4; ++q) _Pragma("unroll")                             \
    for (int p2 = 0; p2 < 2; ++p2) _Pragma("unroll")                          \
    for (int ks = 0; ks < 2; ++ks)                                            \
      acc[(mh)*4+q][(nh)*2+p2] = __builtin_amdgcn_mfma_f32_16x16x32_bf16(     \
        ar[q][ks], br[(nh)*2+p2][ks], acc[(mh)*4+q][(nh)*2+p2], 0, 0, 0);     \
    } while(0)
  #define BAR() do { __builtin_amdgcn_sched_barrier(0);                       \
                     asm volatile("s_barrier" ::: "memory");                  \
                     __builtin_amdgcn_sched_barrier(0); } while(0)
  #define LGKM0() do { asm volatile("s_waitcnt lgkmcnt(0)" ::: "memory");     \
                       __builtin_amdgcn_sched_barrier(0); } while(0)

  // prologue: tile0 -> buf0, tile1 -> buf1 (8 gloads each, per wave)
  stA(0,0,0); stA(0,1,0); stB(0,0,0); stB(0,1,0);
  stA(1,0,1); stA(1,1,1); stB(1,0,1); stB(1,1,1);
  asm volatile("s_waitcnt vmcnt(8)" ::: "memory");   // tile0 landed
  BAR();

  #pragma unroll 1
  for (int t = 0; t < 10; ++t){
    const int b = t & 1;
    const char* bufp = lds + b*65536;
    // ---- phase 0: 12 ds_reads; NO stage (A,B regions all still live)
    LDA(0); LDB(0);
    BAR(); LGKM0();
    __builtin_amdgcn_s_setprio(1); MFMAQ(0,0); __builtin_amdgcn_s_setprio(0);
    BAR();
    // ---- phase 1: 4 ds_reads; NO stage
    LDB(1);
    BAR(); LGKM0();
    __builtin_amdgcn_s_setprio(1); MFMAQ(0,1); __builtin_amdgcn_s_setprio(0);
    BAR();
    // ---- phase 2: 8 ds_reads; stage B0,B1(t+2) (B free after ph1 end-bar)
    LDA(1);
    if (t+2 < 10){ stB(b, 0, t+2); stB(b, 1, t+2); }
    BAR(); LGKM0();
    __builtin_amdgcn_s_setprio(1); MFMAQ(1,1); __builtin_amdgcn_s_setprio(0);
    BAR();
    // ---- phase 3: 0 ds_reads; stage A0,A1(t+2) (A free after ph2 end-bar)
    if (t+2 < 10){ stA(b, 0, t+2); stA(b, 1, t+2); }
    BAR();
    __builtin_amdgcn_s_setprio(1); MFMAQ(1,0); __builtin_amdgcn_s_setprio(0);
    if (t < 8) asm volatile("s_waitcnt vmcnt(8)" ::: "memory");
    else       asm volatile("s_waitcnt vmcnt(0)" ::: "memory");
    BAR();
  }
  #undef LDA
  #undef LDB
  #undef MFMAQ
  #undef BAR
  #undef LGKM0

  // ---- epilogue ----
  #pragma unroll
  for (int mt = 0; mt < 8; ++mt)
    #pragma unroll
    for (int nt = 0; nt < 4; ++nt)
      #pragma unroll
      for (int r = 0; r < 4; ++r){
        int m = m0 + wr*128 + mt*16 + g*4 + r;
        int c = n0 + wc*64 + nt*16 + lo;
        if (MODE == 0){
          if (c >= 1920) continue;
          u16 val = f2bf(acc[mt][nt][r]);
          int p = (c >= 1280) ? 2 : (c >= 640) ? 1 : 0;
          int rem = c - p*640;
          if (p == 0)      qb[(size_t)m*640 + rem] = val;
          else if (p == 1) kb[(size_t)m*640 + rem] = val;
          else {
            int h = rem >> 7, d = rem & 127;
            vtb[((size_t)(m >> 8)*5 + h)*32768 + (size_t)d*256 + (m & 255)] = val;
          }
        } else {
          if (c >= 640) continue;
          float v = acc[mt][nt][r] + bf2f(bpw[c]);
          if (f32out) ((float*)outp)[(size_t)m*640 + c] = v;
          else        ((u16*)outp)[(size_t)m*640 + c]   = f2bf(v);
        }
      }
}

// ------------------------------------------------------------------
// Attention: unchanged. grid = 640 blocks, 256 threads.
__global__ __launch_bounds__(256, 1) void attn_fwd(const u16* __restrict__ qb,
    const u16* __restrict__ kb, const u16* __restrict__ vtb, u16* __restrict__ ob){
  __shared__ char smem[147456];
  char* k_lds  = smem;
  char* vt_lds = smem + 65536;
  char* p_lds  = smem + 131072;
  const int tid = threadIdx.x;
  const int bsh = blockIdx.x >> 1;
  const int chalf = (blockIdx.x & 1) * 128;
  const int bs = bsh / 5, h = bsh % 5;
  const u16* kbase = kb + (size_t)bs*256*640 + (size_t)h*128;
  const u16* vbase = vtb + (size_t)bsh*32768;
  #pragma unroll 4
  for (int i = 0; i < 16; ++i){
    int idx = i*256 + tid;
    int e = idx >> 4, cd = idx & 15;
    uint4 kv = *(const uint4*)(kbase + (size_t)e*640 + cd*8);
    *(uint4*)(k_lds + e*256 + ((cd ^ (e & 7)))*16) = kv;
    int d = idx >> 5, ce = idx & 31;
    uint4 vv = *(const uint4*)(vbase + d*256 + ce*8);
    *(uint4*)(vt_lds + d*512 + ((ce ^ (d & 7)))*16) = vv;
  }
  __syncthreads();
  const int lane = tid & 63, wid = tid >> 6;
  const int g = lane >> 4, lo = lane & 15;
  char* pw = p_lds + wid*4096;
  const float scale = 0.08838834764831845f;
  const f32x4 vzero = {0.f, 0.f, 0.f, 0.f};

  for (int mt = 0; mt < 2; ++mt){
    const int crow = chalf + wid*32 + mt*16;
    const u16* qr = qb + ((size_t)bs*256 + crow + lo)*640 + (size_t)h*128;
    bf16x8 qf[4];
    #pragma unroll
    for (int kc = 0; kc < 4; ++kc) qf[kc] = *(const bf16x8*)(qr + kc*32 + g*8);

    f32x4 acc[16];
    #pragma unroll
    for (int et = 0; et < 16; ++et) acc[et] = vzero;
    #pragma unroll
    for (int et = 0; et < 16; ++et)
      #pragma unroll
      for (int kc = 0; kc < 4; ++kc){
        bf16x8 bk = *(const bf16x8*)(k_lds + k_off(et*16 + lo, kc*32 + g*8));
        acc[et] = __builtin_amdgcn_mfma_f32_16x16x32_bf16(qf[kc], bk, acc[et], 0, 0, 0);
      }

    float mx[4] = {-3.0e38f, -3.0e38f, -3.0e38f, -3.0e38f};
    #pragma unroll
    for (int et = 0; et < 16; ++et)
      #pragma unroll
      for (int r = 0; r < 4; ++r){
        float t = acc[et][r] * scale;
        acc[et][r] = t;
        mx[r] = fmaxf(mx[r], t);
      }
    #pragma unroll
    for (int msk = 1; msk < 16; msk <<= 1)
      #pragma unroll
      for (int r = 0; r < 4; ++r) mx[r] = fmaxf(mx[r], __shfl_xor(mx[r], msk));
    float sm[4] = {0.f, 0.f, 0.f, 0.f};
    #pragma unroll
    for (int et = 0; et < 16; ++et)
      #pragma unroll
      for (int r = 0; r < 4; ++r){
        float ex = __expf(acc[et][r] - mx[r]);
        acc[et][r] = ex;
        sm[r] += ex;
      }
    #pragma unroll
    for (int msk = 1; msk < 16; msk <<= 1)
      #pragma unroll
      for (int r = 0; r < 4; ++r) sm[r] += __shfl_xor(sm[r], msk);
    float inv[4];
    #pragma unroll
    for (int r = 0; r < 4; ++r) inv[r] = 1.0f / sm[r];

    f32x4 oacc[8];
    #pragma unroll
    for (int dt = 0; dt < 8; ++dt) oacc[dt] = vzero;

    #pragma unroll
    for (int half = 0; half < 2; ++half){
      #pragma unroll
      for (int et2 = 0; et2 < 8; ++et2){
        int et = half*8 + et2;
        #pragma unroll
        for (int r = 0; r < 4; ++r)
          *(u16*)(pw + p_off(g*4 + r, et2*16 + lo)) = f2bf(acc[et][r] * inv[r]);
      }
      asm volatile("s_waitcnt lgkmcnt(0)" ::: "memory");
      bf16x8 pf[4];
      #pragma unroll
      for (int kc = 0; kc < 4; ++kc) pf[kc] = *(const bf16x8*)(pw + p_off(lo, kc*32 + g*8));
      #pragma unroll
      for (int dt = 0; dt < 8; ++dt)
        #pragma unroll
        for (int kc = 0; kc < 4; ++kc){
          bf16x8 bv = *(const bf16x8*)(vt_lds + vt_off(dt*16 + lo, half*128 + kc*32 + g*8));
          oacc[dt] = __builtin_amdgcn_mfma_f32_16x16x32_bf16(pf[kc], bv, oacc[dt], 0, 0, 0);
        }
      asm volatile("s_waitcnt lgkmcnt(0)" ::: "memory");
    }

    u16* orow = ob + ((size_t)bs*256 + crow)*640 + (size_t)h*128;
    #pragma unroll
    for (int dt = 0; dt < 8; ++dt)
      #pragma unroll
      for (int r = 0; r < 4; ++r)
        orow[(size_t)(g*4 + r)*640 + dt*16 + lo] = f2bf(oacc[dt][r]);
  }
}

// ------------------------------------------------------------------
extern "C" void kernel_launch(void* const* d_in, const int* in_sizes, int n_in,
                              void* d_out, int out_size, void* d_ws, size_t ws_size,
                              hipStream_t stream) {
  (void)in_sizes; (void)n_in; (void)out_size; (void)ws_size;
  char* ws = (char*)d_ws;
  const size_t SZ = (size_t)16384 * 640 * 2;     // 20,971,520 B
  u16* XB   = (u16*)(ws);
  u16* QB   = (u16*)(ws + SZ);
  u16* KB   = (u16*)(ws + 2*SZ);
  u16* VTB  = (u16*)(ws + 3*SZ);
  u16* AT   = XB;                                 // x dead after gemm_qkv
  u16* WSTK = (u16*)(ws + 4*SZ);                  // [2048][640]
  u16* WPAD = WSTK + 1310720;                     // [768][640]
  u16* BPB  = WPAD + 491520;                      // [640]
  unsigned* FLAG = (unsigned*)(BPB + 640);

  k_convert_all<<<3001, 256, 0, stream>>>(d_in[0], d_in[1], d_in[2], d_in[3],
                                          d_in[4], d_in[5], XB, WSTK, WPAD, BPB, FLAG);

  gemm8p<0><<<dim3(64, 8), 512, 0, stream>>>(XB, WSTK, nullptr, QB, KB, VTB, nullptr, FLAG);
  attn_fwd<<<640, 256, 0, stream>>>(QB, KB, VTB, AT);
  gemm8p<1><<<dim3(64, 3), 512, 0, stream>>>(AT, WPAD, BPB, nullptr, nullptr, nullptr, d_out, FLAG);
}

// Round 7
// 164.786 us; speedup vs baseline: 1.1132x; 1.1132x over previous
//
#include <hip/hip_runtime.h>

// B=2, S=32, C=256, L=640, H=5, D=128.  M = B*S*C = 16384, L = 640 = H*D.
//
// ws layout (bytes):
//   XB   @ 0    : x bf16 [16384][640] (only written when input is fp32)
//                 -- reused as attn_out (AT) after attn in all cases
//   QB   @ SZ   : q bf16 [16384][640] (col = h*128+d)
//   KB   @ 2SZ  : k bf16 [16384][640]
//   VTB  @ 3SZ  : v transposed bf16 [320 bsh][128 d][256 e]
//   WSTK @ 4SZ  : Wq|Wk|Wv stacked bf16 [1920][640]
//   WPB         : Wp bf16 [640][640];  BPB: bp bf16 [640];  FLAG: u32

typedef unsigned short u16;
typedef __bf16 bf16x8 __attribute__((ext_vector_type(8)));
typedef float f32x4 __attribute__((ext_vector_type(4)));

__device__ __forceinline__ u16 f2bf(float f){
  union { float f; unsigned u; } v; v.f = f;
  unsigned r = v.u + 0x7fffu + ((v.u >> 16) & 1u);
  return (u16)(r >> 16);
}
__device__ __forceinline__ float bf2f(u16 u){
  union { unsigned u; float f; } v; v.u = ((unsigned)u) << 16;
  return v.f;
}

__device__ __forceinline__ void gload16(const u16* g, char* l){
  __builtin_amdgcn_global_load_lds((const __attribute__((address_space(1))) void*)g,
                                   (__attribute__((address_space(3))) void*)l, 16, 0, 0);
}

// ---- attention LDS swizzles (unchanged) ----
__device__ __forceinline__ int k_off (int e, int d){ return e*256 + (((d>>3) ^ (e&7)))*16 + (d&7)*2; }
__device__ __forceinline__ int vt_off(int d, int e){ return d*512 + (((e>>3) ^ (d&7)))*16 + (e&7)*2; }
__device__ __forceinline__ int p_off (int c, int el){ return c*256 + (((el>>3) ^ ((c>>2)&3)))*16 + (el&7)*2; }

// ------------------------------------------------------------------
// Fused dtype-detect + convert.  When input is ALREADY bf16 (flag==0) the x
// segment (blocks 0..2559) is skipped entirely — gemm_qkv then reads x
// straight from d_in[0].  Weights always copied/converted (small).
// word4 segments: x [0,2621440) | wstk [..+307200) | wp [..+102400) | bp 160.
__global__ __launch_bounds__(256) void k_convert_all(
    const void* __restrict__ xsrc, const void* __restrict__ s1, const void* __restrict__ s2,
    const void* __restrict__ s3, const void* __restrict__ s4, const void* __restrict__ s5,
    u16* __restrict__ xb, u16* __restrict__ wstk, u16* __restrict__ wpb,
    u16* __restrict__ bpb, unsigned* __restrict__ flagOut){
  __shared__ unsigned sflag;
  const int tid = threadIdx.x;
  const u16* xs = (const u16*)xsrc;
  if (tid < 64){
    int cnt = 0;
    for (int i = tid; i < 1024; i += 64){
      unsigned e = (xs[2*i] >> 7) & 0xffu;
      cnt += (e >= 143u) ? 1 : 0;
    }
    #pragma unroll
    for (int m = 1; m < 64; m <<= 1) cnt += __shfl_xor(cnt, m);
    if (tid == 0) sflag = (cnt > 16) ? 1u : 0u;
  }
  __syncthreads();
  const unsigned flag = sflag;
  if (blockIdx.x == 0 && tid == 0) *flagOut = flag;
  if (blockIdx.x < 2560 && flag == 0u) return;     // x stays in d_in[0]

  #pragma unroll
  for (int it = 0; it < 4; ++it){
    size_t i = (size_t)blockIdx.x*1024 + it*256 + tid;
    if (i >= 3031200) break;
    const void* src; size_t off; u16* dp;
    if (i < 2621440){ src = xsrc; off = i; dp = xb + i*4; }
    else {
      size_t j = i - 2621440;
      if (j < 307200){
        int seg = (int)(j / 102400);
        off = j - (size_t)seg*102400;
        src = (seg==0) ? s1 : (seg==1) ? s2 : s3;
        dp = wstk + j*4;
      } else if (j < 409600){
        off = j - 307200; src = s4; dp = wpb + off*4;
      } else { off = j - 409600; src = s5; dp = bpb + off*4; }
    }
    if (flag){
      float4 v = ((const float4*)src)[off];
      ushort4 o;
      o.x = f2bf(v.x); o.y = f2bf(v.y); o.z = f2bf(v.z); o.w = f2bf(v.w);
      *(ushort4*)dp = o;
    } else {
      *(ushort4*)dp = ((const ushort4*)src)[off];
    }
  }
}

// ------------------------------------------------------------------
// 128x128 tile GEMM core, K=640, BK=32, double-buffered 2-phase, 4 waves.
// LDS per buffer 16KB (A 8KB @0, B 8KB @8192); 2 buffers = 32KB total ->
// up to 4 blocks/CU (VGPR<=128 via __launch_bounds__(256,4)).
// LDS layout: PAIRED rows — [64 lines][128B]; line = 2 rows; slot s (16B)
// holds true (parity p>>2, chunk p&3) with p = s ^ (line&7).  Stage writes
// linearly (global_load_lds) from a pre-swizzled global source; reads XOR
// the same key: per-16-lane group spreads over 8 slots 2-way = conflict-free
// (same structure that measured 0 conflicts in round 3).
__device__ __forceinline__ void gemm_core(const u16* __restrict__ Ag, const u16* __restrict__ Bg,
                                          char* lds, f32x4 acc[4][4]){
  const int tid = threadIdx.x;
  const int lane = tid & 63, wid = tid >> 6;
  const int g = lane >> 4, lo = lane & 15;
  const int wm = wid >> 1, wn = wid & 1;
  const f32x4 vzero = {0.f, 0.f, 0.f, 0.f};
  #pragma unroll
  for (int mt = 0; mt < 4; ++mt)
    #pragma unroll
    for (int nt = 0; nt < 4; ++nt) acc[mt][nt] = vzero;

  // staging source pre-swizzle: lane l writes dest line l>>3, slot l&7 of its
  // 8-line (16-row) group -> true p = (l&7)^((l>>3)&7): row += (l>>3)*2+(p>>2),
  // k-chunk = (p&3)*8.
  const int p_ = (lane & 7) ^ ((lane >> 3) & 7);
  const int rowoff = ((lane >> 3) << 1) + (p_ >> 2);
  const int koff = (p_ & 3) * 8;
  const u16* As = Ag + (size_t)(wid*32 + rowoff)*640 + koff;
  const u16* Bs = Bg + (size_t)(wid*32 + rowoff)*640 + koff;

  #define STAGE(b, kt) do {                                                   \
    gload16(As + (kt)*32,          lds + (b)*16384 + wid*2048);               \
    gload16(As + 16*640 + (kt)*32, lds + (b)*16384 + wid*2048 + 1024);        \
    gload16(Bs + (kt)*32,          lds + (b)*16384 + 8192 + wid*2048);        \
    gload16(Bs + 16*640 + (kt)*32, lds + (b)*16384 + 8192 + wid*2048 + 1024); \
  } while(0)

  // read slot key: line&7 = (lo>>1)&7 for all fragments (mt*8, wm*32 etc. are
  // multiples of 8); slot = ((lo&1)*4 + g) ^ that.
  const int sl = ((((lo & 1) << 2) | g) ^ ((lo >> 1) & 7)) * 16;

  #define COMPUTE(b) do {                                                     \
    const char* base_ = lds + (b)*16384;                                      \
    bf16x8 af[4], bfr[4];                                                     \
    _Pragma("unroll")                                                         \
    for (int mt = 0; mt < 4; ++mt)                                            \
      af[mt] = *(const bf16x8*)(base_ + (wm*32 + mt*8 + (lo>>1))*128 + sl);   \
    _Pragma("unroll")                                                         \
    for (int nt = 0; nt < 4; ++nt)                                            \
      bfr[nt] = *(const bf16x8*)(base_ + 8192 + (wn*32 + nt*8 + (lo>>1))*128 + sl); \
    _Pragma("unroll")                                                         \
    for (int mt = 0; mt < 4; ++mt)                                            \
      _Pragma("unroll")                                                       \
      for (int nt = 0; nt < 4; ++nt)                                          \
        acc[mt][nt] = __builtin_amdgcn_mfma_f32_16x16x32_bf16(af[mt], bfr[nt], acc[mt][nt], 0, 0, 0); \
  } while(0)

  STAGE(0, 0);
  __syncthreads();
  #pragma unroll 1
  for (int kt2 = 0; kt2 < 10; ++kt2){
    STAGE(1, 2*kt2 + 1);          // issue next-tile loads before compute
    COMPUTE(0);
    __syncthreads();              // drains vmcnt -> buf1 ready; buf0 reads done
    if (kt2 < 9) STAGE(0, 2*kt2 + 2);
    COMPUTE(1);
    __syncthreads();
  }
  #undef STAGE
  #undef COMPUTE
}

// QKV projection: grid (128 mtiles, 15), by -> proj p = by/5, head h = by%5.
// B rows come from the stacked W [1920][640] at by*128.  A = x directly from
// d_in[0] when already bf16, else the converted XB.
__global__ __launch_bounds__(256, 4) void gemm_qkv(const u16* __restrict__ xraw,
    const u16* __restrict__ xb, const unsigned* __restrict__ flag,
    const u16* __restrict__ wstk,
    u16* __restrict__ qb, u16* __restrict__ kb, u16* __restrict__ vtb){
  __shared__ char smem[32768];
  const int m0 = blockIdx.x * 128;
  const int by = blockIdx.y;
  const u16* Ag = (*flag != 0u) ? xb : xraw;
  f32x4 acc[4][4];
  gemm_core(Ag + (size_t)m0*640, wstk + (size_t)by*128*640, smem, acc);
  const int tid = threadIdx.x, lane = tid & 63, wid = tid >> 6;
  const int g = lane >> 4, lo = lane & 15;
  const int wm = wid >> 1, wn = wid & 1;
  const int p = by / 5, h = by % 5;
  #pragma unroll
  for (int mt = 0; mt < 4; ++mt)
    #pragma unroll
    for (int nt = 0; nt < 4; ++nt)
      #pragma unroll
      for (int r = 0; r < 4; ++r){
        int m  = m0 + wm*64 + mt*16 + g*4 + r;       // global row (b,s,c)
        int nn = wn*64 + nt*16 + lo;                 // d within head, 0..127
        u16 val = f2bf(acc[mt][nt][r]);
        if (p == 0)      qb[(size_t)m*640 + h*128 + nn] = val;
        else if (p == 1) kb[(size_t)m*640 + h*128 + nn] = val;
        else             vtb[((size_t)(m >> 8)*5 + h)*32768 + (size_t)nn*256 + (m & 255)] = val;
      }
}

// Output projection + bias; writes d_out as f32 or bf16 per detected flag.
__global__ __launch_bounds__(256, 4) void gemm_out(const u16* __restrict__ at,
    const u16* __restrict__ wpw, const u16* __restrict__ bpw,
    void* __restrict__ out, const unsigned* __restrict__ flag){
  __shared__ char smem[32768];
  const int m0 = blockIdx.x * 128;
  const int n0 = blockIdx.y * 128;
  f32x4 acc[4][4];
  gemm_core(at + (size_t)m0*640, wpw + (size_t)n0*640, smem, acc);
  const int tid = threadIdx.x, lane = tid & 63, wid = tid >> 6;
  const int g = lane >> 4, lo = lane & 15;
  const int wm = wid >> 1, wn = wid & 1;
  const bool f32out = (*flag != 0u);
  #pragma unroll
  for (int mt = 0; mt < 4; ++mt)
    #pragma unroll
    for (int nt = 0; nt < 4; ++nt){
      int col = n0 + wn*64 + nt*16 + lo;
      float bv = bf2f(bpw[col]);
      #pragma unroll
      for (int r = 0; r < 4; ++r){
        int m = m0 + wm*64 + mt*16 + g*4 + r;
        float v = acc[mt][nt][r] + bv;
        if (f32out) ((float*)out)[(size_t)m*640 + col] = v;
        else        ((u16*)out)[(size_t)m*640 + col]   = f2bf(v);
      }
    }
}

// ------------------------------------------------------------------
// Attention: unchanged. grid = 640 blocks, 256 threads.
__global__ __launch_bounds__(256, 1) void attn_fwd(const u16* __restrict__ qb,
    const u16* __restrict__ kb, const u16* __restrict__ vtb, u16* __restrict__ ob){
  __shared__ char smem[147456];
  char* k_lds  = smem;
  char* vt_lds = smem + 65536;
  char* p_lds  = smem + 131072;
  const int tid = threadIdx.x;
  const int bsh = blockIdx.x >> 1;
  const int chalf = (blockIdx.x & 1) * 128;
  const int bs = bsh / 5, h = bsh % 5;
  const u16* kbase = kb + (size_t)bs*256*640 + (size_t)h*128;
  const u16* vbase = vtb + (size_t)bsh*32768;
  #pragma unroll 4
  for (int i = 0; i < 16; ++i){
    int idx = i*256 + tid;
    int e = idx >> 4, cd = idx & 15;
    uint4 kv = *(const uint4*)(kbase + (size_t)e*640 + cd*8);
    *(uint4*)(k_lds + e*256 + ((cd ^ (e & 7)))*16) = kv;
    int d = idx >> 5, ce = idx & 31;
    uint4 vv = *(const uint4*)(vbase + d*256 + ce*8);
    *(uint4*)(vt_lds + d*512 + ((ce ^ (d & 7)))*16) = vv;
  }
  __syncthreads();
  const int lane = tid & 63, wid = tid >> 6;
  const int g = lane >> 4, lo = lane & 15;
  char* pw = p_lds + wid*4096;
  const float scale = 0.08838834764831845f;
  const f32x4 vzero = {0.f, 0.f, 0.f, 0.f};

  for (int mt = 0; mt < 2; ++mt){
    const int crow = chalf + wid*32 + mt*16;
    const u16* qr = qb + ((size_t)bs*256 + crow + lo)*640 + (size_t)h*128;
    bf16x8 qf[4];
    #pragma unroll
    for (int kc = 0; kc < 4; ++kc) qf[kc] = *(const bf16x8*)(qr + kc*32 + g*8);

    f32x4 acc[16];
    #pragma unroll
    for (int et = 0; et < 16; ++et) acc[et] = vzero;
    #pragma unroll
    for (int et = 0; et < 16; ++et)
      #pragma unroll
      for (int kc = 0; kc < 4; ++kc){
        bf16x8 bk = *(const bf16x8*)(k_lds + k_off(et*16 + lo, kc*32 + g*8));
        acc[et] = __builtin_amdgcn_mfma_f32_16x16x32_bf16(qf[kc], bk, acc[et], 0, 0, 0);
      }

    float mx[4] = {-3.0e38f, -3.0e38f, -3.0e38f, -3.0e38f};
    #pragma unroll
    for (int et = 0; et < 16; ++et)
      #pragma unroll
      for (int r = 0; r < 4; ++r){
        float t = acc[et][r] * scale;
        acc[et][r] = t;
        mx[r] = fmaxf(mx[r], t);
      }
    #pragma unroll
    for (int msk = 1; msk < 16; msk <<= 1)
      #pragma unroll
      for (int r = 0; r < 4; ++r) mx[r] = fmaxf(mx[r], __shfl_xor(mx[r], msk));
    float sm[4] = {0.f, 0.f, 0.f, 0.f};
    #pragma unroll
    for (int et = 0; et < 16; ++et)
      #pragma unroll
      for (int r = 0; r < 4; ++r){
        float ex = __expf(acc[et][r] - mx[r]);
        acc[et][r] = ex;
        sm[r] += ex;
      }
    #pragma unroll
    for (int msk = 1; msk < 16; msk <<= 1)
      #pragma unroll
      for (int r = 0; r < 4; ++r) sm[r] += __shfl_xor(sm[r], msk);
    float inv[4];
    #pragma unroll
    for (int r = 0; r < 4; ++r) inv[r] = 1.0f / sm[r];

    f32x4 oacc[8];
    #pragma unroll
    for (int dt = 0; dt < 8; ++dt) oacc[dt] = vzero;

    #pragma unroll
    for (int half = 0; half < 2; ++half){
      #pragma unroll
      for (int et2 = 0; et2 < 8; ++et2){
        int et = half*8 + et2;
        #pragma unroll
        for (int r = 0; r < 4; ++r)
          *(u16*)(pw + p_off(g*4 + r, et2*16 + lo)) = f2bf(acc[et][r] * inv[r]);
      }
      asm volatile("s_waitcnt lgkmcnt(0)" ::: "memory");
      bf16x8 pf[4];
      #pragma unroll
      for (int kc = 0; kc < 4; ++kc) pf[kc] = *(const bf16x8*)(pw + p_off(lo, kc*32 + g*8));
      #pragma unroll
      for (int dt = 0; dt < 8; ++dt)
        #pragma unroll
        for (int kc = 0; kc < 4; ++kc){
          bf16x8 bv = *(const bf16x8*)(vt_lds + vt_off(dt*16 + lo, half*128 + kc*32 + g*8));
          oacc[dt] = __builtin_amdgcn_mfma_f32_16x16x32_bf16(pf[kc], bv, oacc[dt], 0, 0, 0);
        }
      asm volatile("s_waitcnt lgkmcnt(0)" ::: "memory");
    }

    u16* orow = ob + ((size_t)bs*256 + crow)*640 + (size_t)h*128;
    #pragma unroll
    for (int dt = 0; dt < 8; ++dt)
      #pragma unroll
      for (int r = 0; r < 4; ++r)
        orow[(size_t)(g*4 + r)*640 + dt*16 + lo] = f2bf(oacc[dt][r]);
  }
}

// ------------------------------------------------------------------
extern "C" void kernel_launch(void* const* d_in, const int* in_sizes, int n_in,
                              void* d_out, int out_size, void* d_ws, size_t ws_size,
                              hipStream_t stream) {
  (void)in_sizes; (void)n_in; (void)out_size; (void)ws_size;
  char* ws = (char*)d_ws;
  const size_t SZ = (size_t)16384 * 640 * 2;     // 20,971,520 B
  u16* XB   = (u16*)(ws);
  u16* QB   = (u16*)(ws + SZ);
  u16* KB   = (u16*)(ws + 2*SZ);
  u16* VTB  = (u16*)(ws + 3*SZ);
  u16* AT   = XB;                                 // attn output reuses XB
  u16* WSTK = (u16*)(ws + 4*SZ);                  // [1920][640]
  u16* WPB  = WSTK + 1228800;                     // [640][640]
  u16* BPB  = WPB + 409600;                       // [640]
  unsigned* FLAG = (unsigned*)(BPB + 640);

  k_convert_all<<<2961, 256, 0, stream>>>(d_in[0], d_in[1], d_in[2], d_in[3],
                                          d_in[4], d_in[5], XB, WSTK, WPB, BPB, FLAG);

  gemm_qkv<<<dim3(128, 15), 256, 0, stream>>>((const u16*)d_in[0], XB, FLAG,
                                              WSTK, QB, KB, VTB);
  attn_fwd<<<640, 256, 0, stream>>>(QB, KB, VTB, AT);
  gemm_out<<<dim3(128, 5), 256, 0, stream>>>(AT, WPB, BPB, d_out, FLAG);
}

// Round 8
// 164.550 us; speedup vs baseline: 1.1148x; 1.0014x over previous
//
#include <hip/hip_runtime.h>

// B=2, S=32, C=256, L=640, H=5, D=128.  M = B*S*C = 16384, L = 640 = H*D.
//
// ws layout (bytes):
//   XB   @ 0    : x bf16 [16384][640] (written only when input is fp32)
//                 -- reused as attn_out (AT) after attn in all cases
//   QB   @ SZ   : q bf16 [16384][640] (col = h*128+d)
//   KB   @ 2SZ  : k bf16 [16384][640]
//   VTB  @ 3SZ  : v transposed bf16 [320 bsh][128 d][256 e]
//   WSTK @ 4SZ  : Wq|Wk|Wv stacked bf16 [1920][640]
//   WPB         : Wp bf16 [640][640];  BPB: bp bf16 [640];  FLAG: u32

typedef unsigned short u16;
typedef __bf16 bf16x8 __attribute__((ext_vector_type(8)));
typedef float f32x4 __attribute__((ext_vector_type(4)));

__device__ __forceinline__ u16 f2bf(float f){
  union { float f; unsigned u; } v; v.f = f;
  unsigned r = v.u + 0x7fffu + ((v.u >> 16) & 1u);
  return (u16)(r >> 16);
}
__device__ __forceinline__ float bf2f(u16 u){
  union { unsigned u; float f; } v; v.u = ((unsigned)u) << 16;
  return v.f;
}

__device__ __forceinline__ void gload16(const u16* g, char* l){
  __builtin_amdgcn_global_load_lds((const __attribute__((address_space(1))) void*)g,
                                   (__attribute__((address_space(3))) void*)l, 16, 0, 0);
}

// ---- attention LDS swizzles (unchanged) ----
__device__ __forceinline__ int k_off (int e, int d){ return e*256 + (((d>>3) ^ (e&7)))*16 + (d&7)*2; }
__device__ __forceinline__ int vt_off(int d, int e){ return d*512 + (((e>>3) ^ (d&7)))*16 + (e&7)*2; }
__device__ __forceinline__ int p_off (int c, int el){ return c*256 + (((el>>3) ^ ((c>>2)&3)))*16 + (el&7)*2; }

// ------------------------------------------------------------------
// Fused dtype-detect + convert (x copy skipped when already bf16).
// word4 segments: x [0,2621440) | wstk [..+307200) | wp [..+102400) | bp 160.
__global__ __launch_bounds__(256) void k_convert_all(
    const void* __restrict__ xsrc, const void* __restrict__ s1, const void* __restrict__ s2,
    const void* __restrict__ s3, const void* __restrict__ s4, const void* __restrict__ s5,
    u16* __restrict__ xb, u16* __restrict__ wstk, u16* __restrict__ wpb,
    u16* __restrict__ bpb, unsigned* __restrict__ flagOut){
  __shared__ unsigned sflag;
  const int tid = threadIdx.x;
  const u16* xs = (const u16*)xsrc;
  if (tid < 64){
    int cnt = 0;
    for (int i = tid; i < 1024; i += 64){
      unsigned e = (xs[2*i] >> 7) & 0xffu;
      cnt += (e >= 143u) ? 1 : 0;
    }
    #pragma unroll
    for (int m = 1; m < 64; m <<= 1) cnt += __shfl_xor(cnt, m);
    if (tid == 0) sflag = (cnt > 16) ? 1u : 0u;
  }
  __syncthreads();
  const unsigned flag = sflag;
  if (blockIdx.x == 0 && tid == 0) *flagOut = flag;
  if (blockIdx.x < 2560 && flag == 0u) return;     // x stays in d_in[0]

  #pragma unroll
  for (int it = 0; it < 4; ++it){
    size_t i = (size_t)blockIdx.x*1024 + it*256 + tid;
    if (i >= 3031200) break;
    const void* src; size_t off; u16* dp;
    if (i < 2621440){ src = xsrc; off = i; dp = xb + i*4; }
    else {
      size_t j = i - 2621440;
      if (j < 307200){
        int seg = (int)(j / 102400);
        off = j - (size_t)seg*102400;
        src = (seg==0) ? s1 : (seg==1) ? s2 : s3;
        dp = wstk + j*4;
      } else if (j < 409600){
        off = j - 307200; src = s4; dp = wpb + off*4;
      } else { off = j - 409600; src = s5; dp = bpb + off*4; }
    }
    if (flag){
      float4 v = ((const float4*)src)[off];
      ushort4 o;
      o.x = f2bf(v.x); o.y = f2bf(v.y); o.z = f2bf(v.z); o.w = f2bf(v.w);
      *(ushort4*)dp = o;
    } else {
      *(ushort4*)dp = ((const ushort4*)src)[off];
    }
  }
}

// ------------------------------------------------------------------
// 256x128-tile GEMM core, K=640, BK=32, 8 waves (4M x 2N, 64x64/wave),
// 3-buffer LDS (3 x 24KB = 72KB -> 2 blocks/CU) with DEPTH-2 counted-vmcnt
// prefetch: per K-step t: stage(t+2) ; compute(t) ; s_waitcnt vmcnt(3)
// [= this wave's 3 loads of tile t+1 landed; t+2's 3 still in flight] ;
// fenced barrier.  Prefetch window ~2 K-steps covers L2/L3/HBM latency.
// LDS per buffer: A [256 r][64B] @0, B [128 r][64B] @16384.  Slot-swizzle:
// linear slot s of row r holds true chunk s ^ ((r>>1)&3); staged from a
// pre-swizzled GLOBAL source (global_load_lds dest stays linear), reads XOR
// the same key -> per-quarter-wave 2-way bank alias = free.
__device__ __forceinline__ void gemm_core(const u16* __restrict__ Ag, const u16* __restrict__ Bg,
                                          char* lds, f32x4 acc[4][4]){
  const int tid = threadIdx.x;
  const int lane = tid & 63, wid = tid >> 6;
  const int g = lane >> 4, lo = lane & 15;
  const int wm = wid >> 1, wn = wid & 1;
  const f32x4 vzero = {0.f, 0.f, 0.f, 0.f};
  #pragma unroll
  for (int mt = 0; mt < 4; ++mt)
    #pragma unroll
    for (int nt = 0; nt < 4; ++nt) acc[mt][nt] = vzero;

  // staging source pre-swizzle: lane l -> row (l>>2) of its wave's 16-row
  // group, dest slot l&3, true chunk = (l&3) ^ ((l>>3)&3)  [(row>>1)&3].
  const int srow = lane >> 2;
  const size_t soff = (size_t)(wid*16 + srow)*640 + (size_t)(((lane & 3) ^ ((lane >> 3) & 3)) * 8);
  const u16* As = Ag + soff;          // + 128*640 for second A half
  const u16* Bs = Bg + soff;

  #define STAGE(boff, kt) do {                                               \
    gload16(As + (kt)*32,           lds + (boff) + wid*1024);                \
    gload16(As + 128*640 + (kt)*32, lds + (boff) + 8192 + wid*1024);         \
    gload16(Bs + (kt)*32,           lds + (boff) + 16384 + wid*1024);        \
  } while(0)

  // read slot: g ^ ((row>>1)&3) = g ^ ((lo>>1)&3)  (row-bases are mult of 16)
  const int sl = (g ^ ((lo >> 1) & 3)) * 16;

  #define COMPUTE(boff) do {                                                  \
    const char* base_ = lds + (boff);                                         \
    bf16x8 af[4], bfr[4];                                                     \
    _Pragma("unroll")                                                         \
    for (int mt = 0; mt < 4; ++mt)                                            \
      af[mt] = *(const bf16x8*)(base_ + (wm*64 + mt*16 + lo)*64 + sl);        \
    _Pragma("unroll")                                                         \
    for (int nt = 0; nt < 4; ++nt)                                            \
      bfr[nt] = *(const bf16x8*)(base_ + 16384 + (wn*64 + nt*16 + lo)*64 + sl); \
    _Pragma("unroll")                                                         \
    for (int mt = 0; mt < 4; ++mt)                                            \
      _Pragma("unroll")                                                       \
      for (int nt = 0; nt < 4; ++nt)                                          \
        acc[mt][nt] = __builtin_amdgcn_mfma_f32_16x16x32_bf16(af[mt], bfr[nt], acc[mt][nt], 0, 0, 0); \
  } while(0)

  #define BAR() do { __builtin_amdgcn_sched_barrier(0);                       \
                     asm volatile("s_barrier" ::: "memory");                  \
                     __builtin_amdgcn_sched_barrier(0); } while(0)

  STAGE(0, 0);
  STAGE(24576, 1);
  asm volatile("s_waitcnt vmcnt(3)" ::: "memory");   // tile 0 landed
  BAR();

  int i0 = 0;                                        // buffer of tile t
  #pragma unroll 1
  for (int t = 0; t < 20; ++t){
    int i2 = i0 - 1; if (i2 < 0) i2 = 2;             // (i0+2)%3
    if (t + 2 < 20) STAGE(i2*24576, t+2);
    COMPUTE(i0*24576);
    if (t + 2 < 20)      asm volatile("s_waitcnt vmcnt(3)" ::: "memory");
    else if (t + 1 < 20) asm volatile("s_waitcnt vmcnt(0)" ::: "memory");
    BAR();
    ++i0; if (i0 == 3) i0 = 0;
  }
  #undef STAGE
  #undef COMPUTE
  #undef BAR
}

// QKV projection: grid (64 mtiles, 15 n-tiles of 128).  n-tile is entirely
// inside one projection: p = by/5, h = by%5 (block-uniform).
__global__ __launch_bounds__(512, 4) void gemm_qkv(const u16* __restrict__ xraw,
    const u16* __restrict__ xb, const unsigned* __restrict__ flag,
    const u16* __restrict__ wstk,
    u16* __restrict__ qb, u16* __restrict__ kb, u16* __restrict__ vtb){
  __shared__ char smem[73728];
  const int m0 = blockIdx.x * 256;
  const int by = blockIdx.y;
  const u16* Ag = (*flag != 0u) ? xb : xraw;
  f32x4 acc[4][4];
  gemm_core(Ag + (size_t)m0*640, wstk + (size_t)by*128*640, smem, acc);
  const int tid = threadIdx.x, lane = tid & 63, wid = tid >> 6;
  const int g = lane >> 4, lo = lane & 15;
  const int wm = wid >> 1, wn = wid & 1;
  const int p = by / 5, h = by % 5;
  #pragma unroll
  for (int mt = 0; mt < 4; ++mt)
    #pragma unroll
    for (int nt = 0; nt < 4; ++nt)
      #pragma unroll
      for (int r = 0; r < 4; ++r){
        int m  = m0 + wm*64 + mt*16 + g*4 + r;       // global row (b,s,c)
        int nn = wn*64 + nt*16 + lo;                 // d within head, 0..127
        u16 val = f2bf(acc[mt][nt][r]);
        if (p == 0)      qb[(size_t)m*640 + h*128 + nn] = val;
        else if (p == 1) kb[(size_t)m*640 + h*128 + nn] = val;
        else             vtb[((size_t)(m >> 8)*5 + h)*32768 + (size_t)nn*256 + (m & 255)] = val;
      }
}

// Output projection + bias; writes d_out as f32 or bf16 per detected flag.
__global__ __launch_bounds__(512, 4) void gemm_out(const u16* __restrict__ at,
    const u16* __restrict__ wpw, const u16* __restrict__ bpw,
    void* __restrict__ out, const unsigned* __restrict__ flag){
  __shared__ char smem[73728];
  const int m0 = blockIdx.x * 256;
  const int n0 = blockIdx.y * 128;
  f32x4 acc[4][4];
  gemm_core(at + (size_t)m0*640, wpw + (size_t)n0*640, smem, acc);
  const int tid = threadIdx.x, lane = tid & 63, wid = tid >> 6;
  const int g = lane >> 4, lo = lane & 15;
  const int wm = wid >> 1, wn = wid & 1;
  const bool f32out = (*flag != 0u);
  #pragma unroll
  for (int mt = 0; mt < 4; ++mt)
    #pragma unroll
    for (int nt = 0; nt < 4; ++nt){
      int col = n0 + wn*64 + nt*16 + lo;
      float bv = bf2f(bpw[col]);
      #pragma unroll
      for (int r = 0; r < 4; ++r){
        int m = m0 + wm*64 + mt*16 + g*4 + r;
        float v = acc[mt][nt][r] + bv;
        if (f32out) ((float*)out)[(size_t)m*640 + col] = v;
        else        ((u16*)out)[(size_t)m*640 + col]   = f2bf(v);
      }
    }
}

// ------------------------------------------------------------------
// Attention: unchanged. grid = 640 blocks, 256 threads.
__global__ __launch_bounds__(256, 1) void attn_fwd(const u16* __restrict__ qb,
    const u16* __restrict__ kb, const u16* __restrict__ vtb, u16* __restrict__ ob){
  __shared__ char smem[147456];
  char* k_lds  = smem;
  char* vt_lds = smem + 65536;
  char* p_lds  = smem + 131072;
  const int tid = threadIdx.x;
  const int bsh = blockIdx.x >> 1;
  const int chalf = (blockIdx.x & 1) * 128;
  const int bs = bsh / 5, h = bsh % 5;
  const u16* kbase = kb + (size_t)bs*256*640 + (size_t)h*128;
  const u16* vbase = vtb + (size_t)bsh*32768;
  #pragma unroll 4
  for (int i = 0; i < 16; ++i){
    int idx = i*256 + tid;
    int e = idx >> 4, cd = idx & 15;
    uint4 kv = *(const uint4*)(kbase + (size_t)e*640 + cd*8);
    *(uint4*)(k_lds + e*256 + ((cd ^ (e & 7)))*16) = kv;
    int d = idx >> 5, ce = idx & 31;
    uint4 vv = *(const uint4*)(vbase + d*256 + ce*8);
    *(uint4*)(vt_lds + d*512 + ((ce ^ (d & 7)))*16) = vv;
  }
  __syncthreads();
  const int lane = tid & 63, wid = tid >> 6;
  const int g = lane >> 4, lo = lane & 15;
  char* pw = p_lds + wid*4096;
  const float scale = 0.08838834764831845f;
  const f32x4 vzero = {0.f, 0.f, 0.f, 0.f};

  for (int mt = 0; mt < 2; ++mt){
    const int crow = chalf + wid*32 + mt*16;
    const u16* qr = qb + ((size_t)bs*256 + crow + lo)*640 + (size_t)h*128;
    bf16x8 qf[4];
    #pragma unroll
    for (int kc = 0; kc < 4; ++kc) qf[kc] = *(const bf16x8*)(qr + kc*32 + g*8);

    f32x4 acc[16];
    #pragma unroll
    for (int et = 0; et < 16; ++et) acc[et] = vzero;
    #pragma unroll
    for (int et = 0; et < 16; ++et)
      #pragma unroll
      for (int kc = 0; kc < 4; ++kc){
        bf16x8 bk = *(const bf16x8*)(k_lds + k_off(et*16 + lo, kc*32 + g*8));
        acc[et] = __builtin_amdgcn_mfma_f32_16x16x32_bf16(qf[kc], bk, acc[et], 0, 0, 0);
      }

    float mx[4] = {-3.0e38f, -3.0e38f, -3.0e38f, -3.0e38f};
    #pragma unroll
    for (int et = 0; et < 16; ++et)
      #pragma unroll
      for (int r = 0; r < 4; ++r){
        float t = acc[et][r] * scale;
        acc[et][r] = t;
        mx[r] = fmaxf(mx[r], t);
      }
    #pragma unroll
    for (int msk = 1; msk < 16; msk <<= 1)
      #pragma unroll
      for (int r = 0; r < 4; ++r) mx[r] = fmaxf(mx[r], __shfl_xor(mx[r], msk));
    float sm[4] = {0.f, 0.f, 0.f, 0.f};
    #pragma unroll
    for (int et = 0; et < 16; ++et)
      #pragma unroll
      for (int r = 0; r < 4; ++r){
        float ex = __expf(acc[et][r] - mx[r]);
        acc[et][r] = ex;
        sm[r] += ex;
      }
    #pragma unroll
    for (int msk = 1; msk < 16; msk <<= 1)
      #pragma unroll
      for (int r = 0; r < 4; ++r) sm[r] += __shfl_xor(sm[r], msk);
    float inv[4];
    #pragma unroll
    for (int r = 0; r < 4; ++r) inv[r] = 1.0f / sm[r];

    f32x4 oacc[8];
    #pragma unroll
    for (int dt = 0; dt < 8; ++dt) oacc[dt] = vzero;

    #pragma unroll
    for (int half = 0; half < 2; ++half){
      #pragma unroll
      for (int et2 = 0; et2 < 8; ++et2){
        int et = half*8 + et2;
        #pragma unroll
        for (int r = 0; r < 4; ++r)
          *(u16*)(pw + p_off(g*4 + r, et2*16 + lo)) = f2bf(acc[et][r] * inv[r]);
      }
      asm volatile("s_waitcnt lgkmcnt(0)" ::: "memory");
      bf16x8 pf[4];
      #pragma unroll
      for (int kc = 0; kc < 4; ++kc) pf[kc] = *(const bf16x8*)(pw + p_off(lo, kc*32 + g*8));
      #pragma unroll
      for (int dt = 0; dt < 8; ++dt)
        #pragma unroll
        for (int kc = 0; kc < 4; ++kc){
          bf16x8 bv = *(const bf16x8*)(vt_lds + vt_off(dt*16 + lo, half*128 + kc*32 + g*8));
          oacc[dt] = __builtin_amdgcn_mfma_f32_16x16x32_bf16(pf[kc], bv, oacc[dt], 0, 0, 0);
        }
      asm volatile("s_waitcnt lgkmcnt(0)" ::: "memory");
    }

    u16* orow = ob + ((size_t)bs*256 + crow)*640 + (size_t)h*128;
    #pragma unroll
    for (int dt = 0; dt < 8; ++dt)
      #pragma unroll
      for (int r = 0; r < 4; ++r)
        orow[(size_t)(g*4 + r)*640 + dt*16 + lo] = f2bf(oacc[dt][r]);
  }
}

// ------------------------------------------------------------------
extern "C" void kernel_launch(void* const* d_in, const int* in_sizes, int n_in,
                              void* d_out, int out_size, void* d_ws, size_t ws_size,
                              hipStream_t stream) {
  (void)in_sizes; (void)n_in; (void)out_size; (void)ws_size;
  char* ws = (char*)d_ws;
  const size_t SZ = (size_t)16384 * 640 * 2;     // 20,971,520 B
  u16* XB   = (u16*)(ws);
  u16* QB   = (u16*)(ws + SZ);
  u16* KB   = (u16*)(ws + 2*SZ);
  u16* VTB  = (u16*)(ws + 3*SZ);
  u16* AT   = XB;                                 // attn output reuses XB
  u16* WSTK = (u16*)(ws + 4*SZ);                  // [1920][640]
  u16* WPB  = WSTK + 1228800;                     // [640][640]
  u16* BPB  = WPB + 409600;                       // [640]
  unsigned* FLAG = (unsigned*)(BPB + 640);

  k_convert_all<<<2961, 256, 0, stream>>>(d_in[0], d_in[1], d_in[2], d_in[3],
                                          d_in[4], d_in[5], XB, WSTK, WPB, BPB, FLAG);

  gemm_qkv<<<dim3(64, 15), 512, 0, stream>>>((const u16*)d_in[0], XB, FLAG,
                                             WSTK, QB, KB, VTB);
  attn_fwd<<<640, 256, 0, stream>>>(QB, KB, VTB, AT);
  gemm_out<<<dim3(64, 5), 512, 0, stream>>>(AT, WPB, BPB, d_out, FLAG);
}

// Round 9
// 159.497 us; speedup vs baseline: 1.1501x; 1.0317x over previous
//
#include <hip/hip_runtime.h>

// B=2, S=32, C=256, L=640, H=5, D=128.  M = B*S*C = 16384, L = 640 = H*D.
//
// ws layout (bytes):
//   XB   @ 0    : x bf16 [16384][640] (written only when input is fp32)
//                 -- reused as attn_out (AT) after attn in all cases
//   QB   @ SZ   : q bf16 [16384][640] (col = h*128+d)
//   KB   @ 2SZ  : k bf16 [16384][640]
//   VTB  @ 3SZ  : v transposed bf16 [320 bsh][128 d][256 e]
//   WSTK @ 4SZ  : Wq|Wk|Wv stacked bf16 [2048][640] (rows 1920.. = 0)
//   WPAD        : Wp bf16 [768][640] (rows 640.. = 0)
//   BPB  bp bf16 [640];  FLAG u32 (1 = inputs fp32)

typedef unsigned short u16;
typedef __bf16 bf16x8 __attribute__((ext_vector_type(8)));
typedef float f32x4 __attribute__((ext_vector_type(4)));

__device__ __forceinline__ u16 f2bf(float f){
  union { float f; unsigned u; } v; v.f = f;
  unsigned r = v.u + 0x7fffu + ((v.u >> 16) & 1u);
  return (u16)(r >> 16);
}
__device__ __forceinline__ float bf2f(u16 u){
  union { unsigned u; float f; } v; v.u = ((unsigned)u) << 16;
  return v.f;
}

__device__ __forceinline__ void gload16(const u16* g, char* l){
  __builtin_amdgcn_global_load_lds((const __attribute__((address_space(1))) void*)g,
                                   (__attribute__((address_space(3))) void*)l, 16, 0, 0);
}

// ---- attention LDS swizzles ----
__device__ __forceinline__ int k_off (int e, int d){ return e*256 + (((d>>3) ^ (e&7)))*16 + (d&7)*2; }
__device__ __forceinline__ int vt_off(int d, int e){ return d*512 + (((e>>3) ^ (d&7)))*16 + (e&7)*2; }
// per-wave P tile [16 c][64 e], rows 128B
__device__ __forceinline__ int p_off2(int c, int el){ return c*128 + (((el>>3) ^ (c&7)))*16 + (el&7)*2; }

// ------------------------------------------------------------------
// Fused dtype-detect + convert; zero-fills N-pad rows; skips x when bf16.
// word4 segments: x [0,2621440) | wstk 307200 | wstk-pad 20480 |
//                 wp 102400 | wp-pad 20480 | bp 160.  total 3072160.
__global__ __launch_bounds__(256) void k_convert_all(
    const void* __restrict__ xsrc, const void* __restrict__ s1, const void* __restrict__ s2,
    const void* __restrict__ s3, const void* __restrict__ s4, const void* __restrict__ s5,
    u16* __restrict__ xb, u16* __restrict__ wstk, u16* __restrict__ wpad,
    u16* __restrict__ bpb, unsigned* __restrict__ flagOut){
  __shared__ unsigned sflag;
  const int tid = threadIdx.x;
  const u16* xs = (const u16*)xsrc;
  if (tid < 64){
    int cnt = 0;
    for (int i = tid; i < 1024; i += 64){
      unsigned e = (xs[2*i] >> 7) & 0xffu;
      cnt += (e >= 143u) ? 1 : 0;
    }
    #pragma unroll
    for (int m = 1; m < 64; m <<= 1) cnt += __shfl_xor(cnt, m);
    if (tid == 0) sflag = (cnt > 16) ? 1u : 0u;
  }
  __syncthreads();
  const unsigned flag = sflag;
  if (blockIdx.x == 0 && tid == 0) *flagOut = flag;
  if (blockIdx.x < 2560 && flag == 0u) return;     // x stays in d_in[0]

  #pragma unroll
  for (int it = 0; it < 4; ++it){
    size_t i = (size_t)blockIdx.x*1024 + it*256 + tid;
    if (i >= 3072160) break;
    const void* src = nullptr; size_t off = 0; u16* dp = nullptr;
    if (i < 2621440){ src = xsrc; off = i; dp = xb + i*4; }
    else {
      size_t j = i - 2621440;
      if (j < 307200){
        int seg = (int)(j / 102400);
        off = j - (size_t)seg*102400;
        src = (seg==0) ? s1 : (seg==1) ? s2 : s3;
        dp = wstk + j*4;
      } else if (j < 327680){
        ushort4 z = {0,0,0,0}; *(ushort4*)(wstk + j*4) = z; continue;
      } else if (j < 430080){
        off = j - 327680; src = s4; dp = wpad + off*4;
      } else if (j < 450560){
        ushort4 z = {0,0,0,0}; *(ushort4*)(wpad + (j-327680)*4) = z; continue;
      } else { off = j - 450560; src = s5; dp = bpb + off*4; }
    }
    if (flag){
      float4 v = ((const float4*)src)[off];
      ushort4 o;
      o.x = f2bf(v.x); o.y = f2bf(v.y); o.z = f2bf(v.z); o.w = f2bf(v.w);
      *(ushort4*)dp = o;
    } else {
      *(ushort4*)dp = ((const ushort4*)src)[off];
    }
  }
}

// ------------------------------------------------------------------
// 256x256-tile GEMM, K=640, BK=32, 8 waves (4M x 2N), PER-WAVE 64x128 out
// (acc 128 VGPR, 32 MFMA per K-step per wave — 2x the old density).
// 3-buffer LDS (3 x 32KB = 96KB): A [256 r][64B] @0, B [256 r][64B] @16384.
// Depth-2 prefetch, counted vmcnt(4) (4 gloads/wave/K-step), fenced BARs.
// Slot swizzle (proven 0-conflict in r7): linear slot s of row r holds true
// chunk s ^ ((r>>1)&3); staged via pre-swizzled GLOBAL source; reads XOR the
// same key -> 2-way bank alias = free.
// MODE 0: qkv scatter epilogue (q/k rowmajor, v transposed; c>=1920 pad skip).
// MODE 1: out-proj + bias (c>=640 skip), f32/bf16 per flag.
template<int MODE>
__global__ __launch_bounds__(512, 2) void gemm_big(
    const u16* __restrict__ xraw, const u16* __restrict__ xb,
    const u16* __restrict__ Bg, const u16* __restrict__ bpw,
    u16* __restrict__ qb, u16* __restrict__ kb, u16* __restrict__ vtb,
    void* __restrict__ outp, const unsigned* __restrict__ flag){
  __shared__ char lds[98304];
  const int tid = threadIdx.x;
  const int lane = tid & 63, wid = tid >> 6;
  const int g = lane >> 4, lo = lane & 15;
  const int wm = wid >> 1, wn = wid & 1;
  const int m0 = blockIdx.x * 256;
  const int n0 = blockIdx.y * 256;
  const u16* Ag = (MODE == 0) ? ((*flag != 0u) ? xb : xraw) : xraw;

  // staging: each gload = 16 rows x 64B; lane l -> row l>>2, dest slot l&3,
  // pre-swizzled true chunk (l&3)^((l>>3)&3)  [= (srow>>1)&3].
  const int srow = lane >> 2;
  const size_t soff = (size_t)srow*640 + (size_t)(((lane & 3) ^ ((lane >> 3) & 3)) * 8);
  const u16* As = Ag + (size_t)(m0 + wid*32)*640 + soff;
  const u16* Bs = Bg + (size_t)(n0 + wid*32)*640 + soff;

  #define STAGE(boff, kt) do {                                                \
    gload16(As + (kt)*32,          lds + (boff) + wid*2048);                  \
    gload16(As + 16*640 + (kt)*32, lds + (boff) + wid*2048 + 1024);           \
    gload16(Bs + (kt)*32,          lds + (boff) + 16384 + wid*2048);          \
    gload16(Bs + 16*640 + (kt)*32, lds + (boff) + 16384 + wid*2048 + 1024);   \
  } while(0)

  const int sl = (g ^ ((lo >> 1) & 3)) * 16;     // read slot key (lo-only)

  f32x4 acc[4][8];
  const f32x4 vzero = {0.f, 0.f, 0.f, 0.f};
  #pragma unroll
  for (int q = 0; q < 4; ++q)
    #pragma unroll
    for (int p2 = 0; p2 < 8; ++p2) acc[q][p2] = vzero;

  #define COMPUTE(boff) do {                                                  \
    const char* base_ = lds + (boff);                                         \
    bf16x8 af[4], bfr[8];                                                     \
    _Pragma("unroll")                                                         \
    for (int q = 0; q < 4; ++q)                                               \
      af[q] = *(const bf16x8*)(base_ + (wm*64 + q*16 + lo)*64 + sl);          \
    _Pragma("unroll")                                                         \
    for (int p2 = 0; p2 < 8; ++p2)                                            \
      bfr[p2] = *(const bf16x8*)(base_ + 16384 + (wn*128 + p2*16 + lo)*64 + sl); \
    _Pragma("unroll")                                                         \
    for (int q = 0; q < 4; ++q)                                               \
      _Pragma("unroll")                                                       \
      for (int p2 = 0; p2 < 8; ++p2)                                          \
        acc[q][p2] = __builtin_amdgcn_mfma_f32_16x16x32_bf16(af[q], bfr[p2], acc[q][p2], 0, 0, 0); \
  } while(0)

  #define BAR() do { __builtin_amdgcn_sched_barrier(0);                       \
                     asm volatile("s_barrier" ::: "memory");                  \
                     __builtin_amdgcn_sched_barrier(0); } while(0)

  STAGE(0, 0);
  STAGE(32768, 1);
  asm volatile("s_waitcnt vmcnt(4)" ::: "memory");   // tile 0 landed
  BAR();

  int i0 = 0;
  #pragma unroll 1
  for (int t = 0; t < 20; ++t){
    int i2 = i0 - 1; if (i2 < 0) i2 = 2;             // (i0+2)%3
    if (t + 2 < 20) STAGE(i2*32768, t+2);
    COMPUTE(i0*32768);
    if (t + 2 < 20)      asm volatile("s_waitcnt vmcnt(4)" ::: "memory");
    else if (t + 1 < 20) asm volatile("s_waitcnt vmcnt(0)" ::: "memory");
    BAR();
    ++i0; if (i0 == 3) i0 = 0;
  }
  #undef STAGE
  #undef COMPUTE
  #undef BAR

  // ---- epilogue ----
  const bool f32out = (MODE == 1) && (*flag != 0u);
  #pragma unroll
  for (int q = 0; q < 4; ++q)
    #pragma unroll
    for (int p2 = 0; p2 < 8; ++p2)
      #pragma unroll
      for (int r = 0; r < 4; ++r){
        int m = m0 + wm*64 + q*16 + g*4 + r;
        int c = n0 + wn*128 + p2*16 + lo;
        if (MODE == 0){
          if (c >= 1920) continue;
          u16 val = f2bf(acc[q][p2][r]);
          int pp = (c >= 1280) ? 2 : (c >= 640) ? 1 : 0;
          int rem = c - pp*640;
          if (pp == 0)      qb[(size_t)m*640 + rem] = val;
          else if (pp == 1) kb[(size_t)m*640 + rem] = val;
          else {
            int h = rem >> 7, d = rem & 127;
            vtb[((size_t)(m >> 8)*5 + h)*32768 + (size_t)d*256 + (m & 255)] = val;
          }
        } else {
          if (c >= 640) continue;
          float v = acc[q][p2][r] + bf2f(bpw[c]);
          if (f32out) ((float*)outp)[(size_t)m*640 + c] = v;
          else        ((u16*)outp)[(size_t)m*640 + c]   = f2bf(v);
        }
      }
}

// ------------------------------------------------------------------
// Attention: 512 threads / 8 waves, grid = 320 (one block per b,s,h).
// k [256][128] + vT [128][256] staged once per block (was twice).
// Per-wave P tile shrunk to [16 c][64 e] (2 KB): LDS 64+64+16 = 144 KB.
__global__ __launch_bounds__(512, 1) void attn_fwd(const u16* __restrict__ qb,
    const u16* __restrict__ kb, const u16* __restrict__ vtb, u16* __restrict__ ob){
  __shared__ char smem[147456];
  char* k_lds  = smem;               // 64 KiB
  char* vt_lds = smem + 65536;       // 64 KiB
  char* p_lds  = smem + 131072;      // 16 KiB = 8 waves x [16][64]
  const int tid = threadIdx.x;
  const int bsh = blockIdx.x;
  const int bs = bsh / 5, h = bsh % 5;
  const u16* kbase = kb + (size_t)bs*256*640 + (size_t)h*128;
  const u16* vbase = vtb + (size_t)bsh*32768;
  #pragma unroll 4
  for (int i = 0; i < 8; ++i){
    int idx = i*512 + tid;
    int e = idx >> 4, cd = idx & 15;
    uint4 kv = *(const uint4*)(kbase + (size_t)e*640 + cd*8);
    *(uint4*)(k_lds + e*256 + ((cd ^ (e & 7)))*16) = kv;
    int d = idx >> 5, ce = idx & 31;
    uint4 vv = *(const uint4*)(vbase + d*256 + ce*8);
    *(uint4*)(vt_lds + d*512 + ((ce ^ (d & 7)))*16) = vv;
  }
  __syncthreads();
  const int lane = tid & 63, wid = tid >> 6;
  const int g = lane >> 4, lo = lane & 15;
  char* pw = p_lds + wid*2048;
  const float scale = 0.08838834764831845f;
  const f32x4 vzero = {0.f, 0.f, 0.f, 0.f};

  for (int mt = 0; mt < 2; ++mt){
    const int crow = wid*32 + mt*16;
    const u16* qr = qb + ((size_t)bs*256 + crow + lo)*640 + (size_t)h*128;
    bf16x8 qf[4];
    #pragma unroll
    for (int kc = 0; kc < 4; ++kc) qf[kc] = *(const bf16x8*)(qr + kc*32 + g*8);

    f32x4 acc[16];
    #pragma unroll
    for (int et = 0; et < 16; ++et) acc[et] = vzero;
    #pragma unroll
    for (int et = 0; et < 16; ++et)
      #pragma unroll
      for (int kc = 0; kc < 4; ++kc){
        bf16x8 bk = *(const bf16x8*)(k_lds + k_off(et*16 + lo, kc*32 + g*8));
        acc[et] = __builtin_amdgcn_mfma_f32_16x16x32_bf16(qf[kc], bk, acc[et], 0, 0, 0);
      }

    float mx[4] = {-3.0e38f, -3.0e38f, -3.0e38f, -3.0e38f};
    #pragma unroll
    for (int et = 0; et < 16; ++et)
      #pragma unroll
      for (int r = 0; r < 4; ++r){
        float t = acc[et][r] * scale;
        acc[et][r] = t;
        mx[r] = fmaxf(mx[r], t);
      }
    #pragma unroll
    for (int msk = 1; msk < 16; msk <<= 1)
      #pragma unroll
      for (int r = 0; r < 4; ++r) mx[r] = fmaxf(mx[r], __shfl_xor(mx[r], msk));
    float sm[4] = {0.f, 0.f, 0.f, 0.f};
    #pragma unroll
    for (int et = 0; et < 16; ++et)
      #pragma unroll
      for (int r = 0; r < 4; ++r){
        float ex = __expf(acc[et][r] - mx[r]);
        acc[et][r] = ex;
        sm[r] += ex;
      }
    #pragma unroll
    for (int msk = 1; msk < 16; msk <<= 1)
      #pragma unroll
      for (int r = 0; r < 4; ++r) sm[r] += __shfl_xor(sm[r], msk);
    float inv[4];
    #pragma unroll
    for (int r = 0; r < 4; ++r) inv[r] = 1.0f / sm[r];

    f32x4 oacc[8];
    #pragma unroll
    for (int dt = 0; dt < 8; ++dt) oacc[dt] = vzero;

    #pragma unroll
    for (int half = 0; half < 2; ++half)
      #pragma unroll
      for (int sub = 0; sub < 2; ++sub){
        // write P chunk: e-cols [half*128+sub*64, +64)
        #pragma unroll
        for (int et2 = 0; et2 < 4; ++et2){
          int et = half*8 + sub*4 + et2;
          #pragma unroll
          for (int r = 0; r < 4; ++r)
            *(u16*)(pw + p_off2(g*4 + r, et2*16 + lo)) = f2bf(acc[et][r] * inv[r]);
        }
        asm volatile("s_waitcnt lgkmcnt(0)" ::: "memory");
        bf16x8 pf[2];
        #pragma unroll
        for (int kc = 0; kc < 2; ++kc) pf[kc] = *(const bf16x8*)(pw + p_off2(lo, kc*32 + g*8));
        #pragma unroll
        for (int dt = 0; dt < 8; ++dt)
          #pragma unroll
          for (int kc = 0; kc < 2; ++kc){
            bf16x8 bv = *(const bf16x8*)(vt_lds + vt_off(dt*16 + lo, half*128 + sub*64 + kc*32 + g*8));
            oacc[dt] = __builtin_amdgcn_mfma_f32_16x16x32_bf16(pf[kc], bv, oacc[dt], 0, 0, 0);
          }
        asm volatile("s_waitcnt lgkmcnt(0)" ::: "memory");
      }

    u16* orow = ob + ((size_t)bs*256 + crow)*640 + (size_t)h*128;
    #pragma unroll
    for (int dt = 0; dt < 8; ++dt)
      #pragma unroll
      for (int r = 0; r < 4; ++r)
        orow[(size_t)(g*4 + r)*640 + dt*16 + lo] = f2bf(oacc[dt][r]);
  }
}

// ------------------------------------------------------------------
extern "C" void kernel_launch(void* const* d_in, const int* in_sizes, int n_in,
                              void* d_out, int out_size, void* d_ws, size_t ws_size,
                              hipStream_t stream) {
  (void)in_sizes; (void)n_in; (void)out_size; (void)ws_size;
  char* ws = (char*)d_ws;
  const size_t SZ = (size_t)16384 * 640 * 2;     // 20,971,520 B
  u16* XB   = (u16*)(ws);
  u16* QB   = (u16*)(ws + SZ);
  u16* KB   = (u16*)(ws + 2*SZ);
  u16* VTB  = (u16*)(ws + 3*SZ);
  u16* AT   = XB;                                 // attn output reuses XB
  u16* WSTK = (u16*)(ws + 4*SZ);                  // [2048][640]
  u16* WPAD = WSTK + 1310720;                     // [768][640]
  u16* BPB  = WPAD + 491520;                      // [640]
  unsigned* FLAG = (unsigned*)(BPB + 640);

  k_convert_all<<<3001, 256, 0, stream>>>(d_in[0], d_in[1], d_in[2], d_in[3],
                                          d_in[4], d_in[5], XB, WSTK, WPAD, BPB, FLAG);

  gemm_big<0><<<dim3(64, 8), 512, 0, stream>>>((const u16*)d_in[0], XB, WSTK,
                                               nullptr, QB, KB, VTB, nullptr, FLAG);
  attn_fwd<<<320, 512, 0, stream>>>(QB, KB, VTB, AT);
  gemm_big<1><<<dim3(64, 3), 512, 0, stream>>>(AT, AT, WPAD, BPB,
                                               nullptr, nullptr, nullptr, d_out, FLAG);
}

// Round 10
// 147.311 us; speedup vs baseline: 1.2453x; 1.0827x over previous
//
#include <hip/hip_runtime.h>

// B=2, S=32, C=256, L=640, H=5, D=128.  M = B*S*C = 16384, L = 640 = H*D.
//
// ws layout (bytes):
//   XB   @ 0    : x bf16 [16384][640] (written only when input is fp32)
//                 -- reused as attn_out (AT) after attn in all cases
//   QB   @ SZ   : q bf16 [16384][640] (col = h*128+d)
//   KB   @ 2SZ  : k bf16 [16384][640]
//   VTB  @ 3SZ  : v transposed bf16 [320 bsh][128 d][256 e]
//   WPK  @ 4SZ  : Wq|Wk|Wv packed FRAG-ORDER [120 nt][20 kb][64 lane][8]
//   WPPK        : Wp packed frag-order [40 nt][20 kb][64][8]
//   BPB  bp bf16 [640];  FLAG u32 (1 = inputs fp32)

typedef unsigned short u16;
typedef __bf16 bf16x8 __attribute__((ext_vector_type(8)));
typedef float f32x4 __attribute__((ext_vector_type(4)));

__device__ __forceinline__ u16 f2bf(float f){
  union { float f; unsigned u; } v; v.f = f;
  unsigned r = v.u + 0x7fffu + ((v.u >> 16) & 1u);
  return (u16)(r >> 16);
}
__device__ __forceinline__ float bf2f(u16 u){
  union { unsigned u; float f; } v; v.u = ((unsigned)u) << 16;
  return v.f;
}

__device__ __forceinline__ void gload16(const u16* g, char* l){
  __builtin_amdgcn_global_load_lds((const __attribute__((address_space(1))) void*)g,
                                   (__attribute__((address_space(3))) void*)l, 16, 0, 0);
}

// ---- attention LDS swizzles ----
__device__ __forceinline__ int k_off (int e, int d){ return e*256 + (((d>>3) ^ (e&7)))*16 + (d&7)*2; }
__device__ __forceinline__ int vt_off(int d, int e){ return d*512 + (((e>>3) ^ (d&7)))*16 + (e&7)*2; }
__device__ __forceinline__ int p_off2(int c, int el){ return c*128 + (((el>>3) ^ (c&7)))*16 + (el&7)*2; }

// ------------------------------------------------------------------
// Fused dtype-detect + convert + WEIGHT REPACK into MFMA fragment order.
// Packed u16 index P = (((nt*20 + kb)*4 + g)*16 + lo)*8 + e  holds
// W[nt*16+lo][kb*32 + g*8 + e]  -> a wave's B-frag load is base + lane*16B,
// perfectly coalesced, no LDS needed for B.
// word4 segments: x [0,2621440) | wqkv-pack 307200 | wp-pack 102400 | bp 40.
__global__ __launch_bounds__(256) void k_convert_all(
    const void* __restrict__ xsrc, const void* __restrict__ s1, const void* __restrict__ s2,
    const void* __restrict__ s3, const void* __restrict__ s4, const void* __restrict__ s5,
    u16* __restrict__ xb, u16* __restrict__ wpk, u16* __restrict__ wppk,
    u16* __restrict__ bpb, unsigned* __restrict__ flagOut){
  __shared__ unsigned sflag;
  const int tid = threadIdx.x;
  const u16* xs = (const u16*)xsrc;
  if (tid < 64){
    int cnt = 0;
    for (int i = tid; i < 1024; i += 64){
      unsigned e = (xs[2*i] >> 7) & 0xffu;
      cnt += (e >= 143u) ? 1 : 0;
    }
    #pragma unroll
    for (int m = 1; m < 64; m <<= 1) cnt += __shfl_xor(cnt, m);
    if (tid == 0) sflag = (cnt > 16) ? 1u : 0u;
  }
  __syncthreads();
  const unsigned flag = sflag;
  if (blockIdx.x == 0 && tid == 0) *flagOut = flag;
  if (blockIdx.x < 2560 && flag == 0u) return;     // x stays in d_in[0]

  #pragma unroll
  for (int it = 0; it < 4; ++it){
    size_t i = (size_t)blockIdx.x*1024 + it*256 + tid;
    if (i >= 3031200) break;
    const void* src; size_t off; u16* dp;
    if (i < 2621440){ src = xsrc; off = i; dp = xb + i*4; }
    else {
      size_t j = i - 2621440;
      if (j < 409600){
        // weight repack (wqkv: j<307200, wp: j>=307200)
        int iswp = (j >= 307200);
        int j2 = iswp ? (int)(j - 307200) : (int)j;
        int P = j2 * 4;
        int eo = P & 7;                  // 0 or 4
        int grp = P >> 3;
        int lo = grp & 15, g = (grp >> 4) & 3;
        int t2 = grp >> 6;
        int kb = t2 % 20, nt = t2 / 20;
        int n = nt*16 + lo;
        int k = kb*32 + g*8 + eo;
        if (iswp){
          src = s4; off = (size_t)n*160 + (k >> 2); dp = wppk + (size_t)j2*4;
        } else {
          int seg = n / 640, r = n % 640;
          src = (seg==0) ? s1 : (seg==1) ? s2 : s3;
          off = (size_t)r*160 + (k >> 2); dp = wpk + (size_t)j2*4;
        }
      } else { off = j - 409600; src = s5; dp = bpb + off*4; }
    }
    if (flag){
      float4 v = ((const float4*)src)[off];
      ushort4 o;
      o.x = f2bf(v.x); o.y = f2bf(v.y); o.z = f2bf(v.z); o.w = f2bf(v.w);
      *(ushort4*)dp = o;
    } else {
      *(ushort4*)dp = ((const ushort4*)src)[off];
    }
  }
}

// ------------------------------------------------------------------
// 128x128-tile GEMM, K=640, BK=64, 4 waves (2x2, 64x64/wave).
// A: r3's PROVEN path — double-buffered 32KB LDS via global_load_lds,
// XOR slot swizzle (0 measured conflicts), 1 barrier per K-step.
// B: REGISTER-DIRECT from frag-order packed weights (L2-resident) — one
// coalesced 16B/lane global load per fragment.  No LDS, no barrier for B.
// 3 blocks/CU (32KB LDS, VGPR capped by __launch_bounds__(256,3)).
// MODE 0: qkv scatter epilogue (by -> p=by/5, h=by%5). MODE 1: +bias.
template<int MODE>
__global__ __launch_bounds__(256, 3) void gemm_rp(
    const u16* __restrict__ xraw, const u16* __restrict__ xb,
    const u16* __restrict__ bpk, const u16* __restrict__ bpw,
    u16* __restrict__ qb, u16* __restrict__ kb, u16* __restrict__ vtb,
    void* __restrict__ outp, const unsigned* __restrict__ flag){
  __shared__ char lds[32768];
  const int tid = threadIdx.x;
  const int lane = tid & 63, wid = tid >> 6;
  const int g = lane >> 4, lo = lane & 15;
  const int wm = wid >> 1, wn = wid & 1;
  const int m0 = blockIdx.x * 128;
  const int byn8 = blockIdx.y * 8;                 // base n-tile (of 16)
  const u16* Ag = (MODE == 0) ? ((*flag != 0u) ? xb : xraw) : xraw;
  const u16* Ax = Ag + (size_t)m0*640;

  // A staging (r3 verbatim): chunk 1KB = 8 rows x 8 slots; lane -> row l>>3,
  // slot l&7; source pre-swizzled true chunk (l&7)^(l>>3).
  const int srow = lane >> 3;
  const size_t soff = (size_t)srow*640 + (size_t)(((lane & 7) ^ srow) * 8);

  #define STAGE(b, kt) do { _Pragma("unroll")                                 \
    for (int cc = 0; cc < 4; ++cc){                                           \
      int c_ = wid*4 + cc;                                                    \
      gload16(Ax + (size_t)(kt)*64 + (size_t)c_*8*640 + soff,                 \
              lds + (b)*16384 + c_*1024);                                     \
    } } while(0)

  bf16x8 bfr[4][2];
  // B frag: packed group (ntile*20+kb) is 512 u16 = 64 lanes x 8 elems.
  #define LOADB(kt) do { _Pragma("unroll")                                    \
    for (int nt = 0; nt < 4; ++nt) _Pragma("unroll")                          \
      for (int ks = 0; ks < 2; ++ks)                                          \
        bfr[nt][ks] = *(const bf16x8*)(bpk +                                  \
          (((size_t)(byn8 + wn*4 + nt)*20 + (kt)*2 + ks) << 9) + lane*8);     \
  } while(0)

  f32x4 acc[4][4];
  const f32x4 vzero = {0.f, 0.f, 0.f, 0.f};
  #pragma unroll
  for (int mt = 0; mt < 4; ++mt)
    #pragma unroll
    for (int nt = 0; nt < 4; ++nt) acc[mt][nt] = vzero;

  #define COMPUTE(b) do { _Pragma("unroll")                                   \
    for (int ks = 0; ks < 2; ++ks){                                           \
      bf16x8 af[4];                                                           \
      _Pragma("unroll")                                                       \
      for (int mt = 0; mt < 4; ++mt)                                          \
        af[mt] = *(const bf16x8*)(lds + (b)*16384 +                           \
                   (wm*64 + mt*16 + lo)*128 + (((ks*4+g) ^ (lo&7))*16));      \
      _Pragma("unroll")                                                       \
      for (int mt = 0; mt < 4; ++mt) _Pragma("unroll")                        \
        for (int nt = 0; nt < 4; ++nt)                                        \
          acc[mt][nt] = __builtin_amdgcn_mfma_f32_16x16x32_bf16(              \
              af[mt], bfr[nt][ks], acc[mt][nt], 0, 0, 0);                     \
    } } while(0)

  STAGE(0, 0);
  __syncthreads();
  #pragma unroll 1
  for (int kt2 = 0; kt2 < 5; ++kt2){
    LOADB(2*kt2);                     // B(t) regs first (wait won't drain stage)
    STAGE(1, 2*kt2 + 1);              // A(t+1) into other buffer
    COMPUTE(0);
    __syncthreads();
    LOADB(2*kt2 + 1);
    if (kt2 < 4) STAGE(0, 2*kt2 + 2);
    COMPUTE(1);
    __syncthreads();
  }
  #undef STAGE
  #undef LOADB
  #undef COMPUTE

  // ---- epilogue ----
  const bool f32out = (MODE == 1) && (*flag != 0u);
  const int p = blockIdx.y / 5, h = blockIdx.y % 5;
  #pragma unroll
  for (int mt = 0; mt < 4; ++mt)
    #pragma unroll
    for (int nt = 0; nt < 4; ++nt)
      #pragma unroll
      for (int r = 0; r < 4; ++r){
        int m  = m0 + wm*64 + mt*16 + g*4 + r;
        int nn = wn*64 + nt*16 + lo;               // 0..127 within the 128-col tile
        if (MODE == 0){
          u16 val = f2bf(acc[mt][nt][r]);
          if (p == 0)      qb[(size_t)m*640 + h*128 + nn] = val;
          else if (p == 1) kb[(size_t)m*640 + h*128 + nn] = val;
          else             vtb[((size_t)(m >> 8)*5 + h)*32768 + (size_t)nn*256 + (m & 255)] = val;
        } else {
          int col = blockIdx.y*128 + nn;
          float v = acc[mt][nt][r] + bf2f(bpw[col]);
          if (f32out) ((float*)outp)[(size_t)m*640 + col] = v;
          else        ((u16*)outp)[(size_t)m*640 + col]   = f2bf(v);
        }
      }
}

// ------------------------------------------------------------------
// Attention (r9, passed): 512 threads / 8 waves, grid = 320.
__global__ __launch_bounds__(512, 1) void attn_fwd(const u16* __restrict__ qb,
    const u16* __restrict__ kb, const u16* __restrict__ vtb, u16* __restrict__ ob){
  __shared__ char smem[147456];
  char* k_lds  = smem;
  char* vt_lds = smem + 65536;
  char* p_lds  = smem + 131072;
  const int tid = threadIdx.x;
  const int bsh = blockIdx.x;
  const int bs = bsh / 5, h = bsh % 5;
  const u16* kbase = kb + (size_t)bs*256*640 + (size_t)h*128;
  const u16* vbase = vtb + (size_t)bsh*32768;
  #pragma unroll 4
  for (int i = 0; i < 8; ++i){
    int idx = i*512 + tid;
    int e = idx >> 4, cd = idx & 15;
    uint4 kv = *(const uint4*)(kbase + (size_t)e*640 + cd*8);
    *(uint4*)(k_lds + e*256 + ((cd ^ (e & 7)))*16) = kv;
    int d = idx >> 5, ce = idx & 31;
    uint4 vv = *(const uint4*)(vbase + d*256 + ce*8);
    *(uint4*)(vt_lds + d*512 + ((ce ^ (d & 7)))*16) = vv;
  }
  __syncthreads();
  const int lane = tid & 63, wid = tid >> 6;
  const int g = lane >> 4, lo = lane & 15;
  char* pw = p_lds + wid*2048;
  const float scale = 0.08838834764831845f;
  const f32x4 vzero = {0.f, 0.f, 0.f, 0.f};

  for (int mt = 0; mt < 2; ++mt){
    const int crow = wid*32 + mt*16;
    const u16* qr = qb + ((size_t)bs*256 + crow + lo)*640 + (size_t)h*128;
    bf16x8 qf[4];
    #pragma unroll
    for (int kc = 0; kc < 4; ++kc) qf[kc] = *(const bf16x8*)(qr + kc*32 + g*8);

    f32x4 acc[16];
    #pragma unroll
    for (int et = 0; et < 16; ++et) acc[et] = vzero;
    #pragma unroll
    for (int et = 0; et < 16; ++et)
      #pragma unroll
      for (int kc = 0; kc < 4; ++kc){
        bf16x8 bk = *(const bf16x8*)(k_lds + k_off(et*16 + lo, kc*32 + g*8));
        acc[et] = __builtin_amdgcn_mfma_f32_16x16x32_bf16(qf[kc], bk, acc[et], 0, 0, 0);
      }

    float mx[4] = {-3.0e38f, -3.0e38f, -3.0e38f, -3.0e38f};
    #pragma unroll
    for (int et = 0; et < 16; ++et)
      #pragma unroll
      for (int r = 0; r < 4; ++r){
        float t = acc[et][r] * scale;
        acc[et][r] = t;
        mx[r] = fmaxf(mx[r], t);
      }
    #pragma unroll
    for (int msk = 1; msk < 16; msk <<= 1)
      #pragma unroll
      for (int r = 0; r < 4; ++r) mx[r] = fmaxf(mx[r], __shfl_xor(mx[r], msk));
    float sm[4] = {0.f, 0.f, 0.f, 0.f};
    #pragma unroll
    for (int et = 0; et < 16; ++et)
      #pragma unroll
      for (int r = 0; r < 4; ++r){
        float ex = __expf(acc[et][r] - mx[r]);
        acc[et][r] = ex;
        sm[r] += ex;
      }
    #pragma unroll
    for (int msk = 1; msk < 16; msk <<= 1)
      #pragma unroll
      for (int r = 0; r < 4; ++r) sm[r] += __shfl_xor(sm[r], msk);
    float inv[4];
    #pragma unroll
    for (int r = 0; r < 4; ++r) inv[r] = 1.0f / sm[r];

    f32x4 oacc[8];
    #pragma unroll
    for (int dt = 0; dt < 8; ++dt) oacc[dt] = vzero;

    #pragma unroll
    for (int half = 0; half < 2; ++half)
      #pragma unroll
      for (int sub = 0; sub < 2; ++sub){
        #pragma unroll
        for (int et2 = 0; et2 < 4; ++et2){
          int et = half*8 + sub*4 + et2;
          #pragma unroll
          for (int r = 0; r < 4; ++r)
            *(u16*)(pw + p_off2(g*4 + r, et2*16 + lo)) = f2bf(acc[et][r] * inv[r]);
        }
        asm volatile("s_waitcnt lgkmcnt(0)" ::: "memory");
        bf16x8 pf[2];
        #pragma unroll
        for (int kc = 0; kc < 2; ++kc) pf[kc] = *(const bf16x8*)(pw + p_off2(lo, kc*32 + g*8));
        #pragma unroll
        for (int dt = 0; dt < 8; ++dt)
          #pragma unroll
          for (int kc = 0; kc < 2; ++kc){
            bf16x8 bv = *(const bf16x8*)(vt_lds + vt_off(dt*16 + lo, half*128 + sub*64 + kc*32 + g*8));
            oacc[dt] = __builtin_amdgcn_mfma_f32_16x16x32_bf16(pf[kc], bv, oacc[dt], 0, 0, 0);
          }
        asm volatile("s_waitcnt lgkmcnt(0)" ::: "memory");
      }

    u16* orow = ob + ((size_t)bs*256 + crow)*640 + (size_t)h*128;
    #pragma unroll
    for (int dt = 0; dt < 8; ++dt)
      #pragma unroll
      for (int r = 0; r < 4; ++r)
        orow[(size_t)(g*4 + r)*640 + dt*16 + lo] = f2bf(oacc[dt][r]);
  }
}

// ------------------------------------------------------------------
extern "C" void kernel_launch(void* const* d_in, const int* in_sizes, int n_in,
                              void* d_out, int out_size, void* d_ws, size_t ws_size,
                              hipStream_t stream) {
  (void)in_sizes; (void)n_in; (void)out_size; (void)ws_size;
  char* ws = (char*)d_ws;
  const size_t SZ = (size_t)16384 * 640 * 2;     // 20,971,520 B
  u16* XB   = (u16*)(ws);
  u16* QB   = (u16*)(ws + SZ);
  u16* KB   = (u16*)(ws + 2*SZ);
  u16* VTB  = (u16*)(ws + 3*SZ);
  u16* AT   = XB;                                 // attn output reuses XB
  u16* WPK  = (u16*)(ws + 4*SZ);                  // packed qkv W: 1,228,800 u16
  u16* WPPK = WPK + 1228800;                      // packed Wp:     409,600 u16
  u16* BPB  = WPPK + 409600;                      // [640]
  unsigned* FLAG = (unsigned*)(BPB + 640);

  k_convert_all<<<2961, 256, 0, stream>>>(d_in[0], d_in[1], d_in[2], d_in[3],
                                          d_in[4], d_in[5], XB, WPK, WPPK, BPB, FLAG);

  gemm_rp<0><<<dim3(128, 15), 256, 0, stream>>>((const u16*)d_in[0], XB, WPK,
                                                nullptr, QB, KB, VTB, nullptr, FLAG);
  attn_fwd<<<320, 512, 0, stream>>>(QB, KB, VTB, AT);
  gemm_rp<1><<<dim3(128, 5), 256, 0, stream>>>(AT, AT, WPPK, BPB,
                                               nullptr, nullptr, nullptr, d_out, FLAG);
}